// Round 13
// baseline (142.393 us; speedup 1.0000x reference)
//
#include <hip/hip_runtime.h>

#define CDIM 2048
#define BATCH 32
#define K2 4096
#define BN 64
#define BK 128
#define KT (K2 / BK)    // 32
#define NT (CDIM / BN)  // 32

typedef float f32x4 __attribute__((ext_vector_type(4)));

// ---- GEMM partial (R7): partial[kt] = xcat[:, k0:k0+BK] @ W[:, k0:k0+BK]^T ----
__global__ __launch_bounds__(256) void gemm_partial_k(
    const float* __restrict__ x1, const float* __restrict__ x2,
    const float* __restrict__ W, float* __restrict__ partial)
{
    __shared__ float lds[BN * BK + BATCH * BK];
    float* Wt = lds;
    float* Xs = lds + BN * BK;

    const int nt = blockIdx.x, kt = blockIdx.y;
    const int i0 = nt * BN, k0 = kt * BK;
    const int t = threadIdx.x;
    const int lane = t & 63, ks = t >> 6;
    const int cg8 = lane & 7, bg = lane >> 3;

    const float* xsrc = (k0 < CDIM) ? x1 : x2;
    const int kk0 = k0 & (CDIM - 1);

    #pragma unroll
    for (int r = 0; r < 8; ++r) {
        int f = t + 256 * r;
        int row = f >> 5, kc = f & 31;
        float4 v = *reinterpret_cast<const float4*>(W + (size_t)(i0 + row) * K2 + k0 + kc * 4);
        int sc = kc ^ ((row >> 3) & 7);
        *reinterpret_cast<float4*>(&Wt[row * BK + sc * 4]) = v;
    }
    #pragma unroll
    for (int r = 0; r < 4; ++r) {
        int f = t + 256 * r;
        int row = f >> 5, kc = f & 31;
        float4 v = *reinterpret_cast<const float4*>(xsrc + row * CDIM + kk0 + kc * 4);
        int sc = kc ^ ((row >> 2) & 7);
        *reinterpret_cast<float4*>(&Xs[row * BK + sc * 4]) = v;
    }
    __syncthreads();

    float acc[4][8] = {};
    #pragma unroll 2
    for (int s = 0; s < 8; ++s) {
        const int kc = ks * 8 + s;
        f32x4 xv[4], wv[8];
        #pragma unroll
        for (int bb = 0; bb < 4; ++bb)
            xv[bb] = *reinterpret_cast<const f32x4*>(&Xs[(4 * bg + bb) * BK + (kc ^ bg) * 4]);
        #pragma unroll
        for (int cc = 0; cc < 8; ++cc)
            wv[cc] = *reinterpret_cast<const f32x4*>(&Wt[(8 * cg8 + cc) * BK + (kc ^ cg8) * 4]);
        #pragma unroll
        for (int bb = 0; bb < 4; ++bb)
            #pragma unroll
            for (int cc = 0; cc < 8; ++cc)
                #pragma unroll
                for (int w = 0; w < 4; ++w)
                    acc[bb][cc] = fmaf(xv[bb][w], wv[cc][w], acc[bb][cc]);
    }

    __syncthreads();
    float* accS = lds;
    #pragma unroll
    for (int bb = 0; bb < 4; ++bb)
        #pragma unroll
        for (int cc = 0; cc < 8; ++cc)
            accS[(ks * 64 + lane) * 33 + bb * 8 + cc] = acc[bb][cc];
    __syncthreads();

    {
        const int l0 = t >> 2, q = t & 3;
        float s0[8];
        #pragma unroll
        for (int j = 0; j < 8; ++j) {
            float s = 0.f;
            #pragma unroll
            for (int k = 0; k < 4; ++k)
                s += accS[(k * 64 + l0) * 33 + q * 8 + j];
            s0[j] = s;
        }
        const int b_row = 4 * (l0 >> 3) + q;
        const int icol  = 8 * (l0 & 7);
        float* dst = partial + (size_t)kt * (BATCH * CDIM) + b_row * CDIM + i0 + icol;
        *reinterpret_cast<float4*>(dst)     = make_float4(s0[0], s0[1], s0[2], s0[3]);
        *reinterpret_cast<float4*>(dst + 4) = make_float4(s0[4], s0[5], s0[6], s0[7]);
    }
}

__global__ __launch_bounds__(256) void reduce_x_k(
    const float* __restrict__ partial, const float* __restrict__ bias,
    float* __restrict__ x)
{
    int idx = blockIdx.x * 256 + threadIdx.x;
    float s = 0.f;
    #pragma unroll
    for (int kt = 0; kt < KT; ++kt) s += partial[(size_t)kt * (BATCH * CDIM) + idx];
    x[idx] = s + bias[idx & (CDIM - 1)];
}

// ---- Attention (R7 math) with write-locality mapping:
//  * wave->row interleave: i = rg*64 + r*4 + wv  (4 consecutive rows per step,
//    one 32 KB contiguous write window per block)
//  * XCD-aware block swizzle: blocks resident on one XCD cover a contiguous
//    64 MB span of att. ----
__global__ __launch_bounds__(256) void attn_k(
    const float* __restrict__ x, const float* __restrict__ x1,
    const float* __restrict__ x2, float* __restrict__ out1,
    float* __restrict__ out2, float* __restrict__ att)
{
    __shared__ float xs[CDIM];
    __shared__ float xs1[CDIM];
    __shared__ float xs2[CDIM];
    __shared__ float wred[8];
    // bijective XCD swizzle (1024 blocks, 8 XCDs, 128 per XCD)
    const int bid = blockIdx.x;
    const int swz = (bid & 7) * 128 + (bid >> 3);
    const int b = swz >> 5, rg = swz & 31;
    const int t = threadIdx.x;
    const int lane = t & 63, wv = t >> 6;
    const float* xb  = x  + b * CDIM;
    const float* x1b = x1 + b * CDIM;
    const float* x2b = x2 + b * CDIM;

    #pragma unroll
    for (int r = 0; r < 2; ++r) {
        int f = (t + 256 * r) * 4;
        *reinterpret_cast<float4*>(&xs[f])  = *reinterpret_cast<const float4*>(xb  + f);
        *reinterpret_cast<float4*>(&xs1[f]) = *reinterpret_cast<const float4*>(x1b + f);
        *reinterpret_cast<float4*>(&xs2[f]) = *reinterpret_cast<const float4*>(x2b + f);
    }
    __syncthreads();

    float mn = 1e30f, mx = -1e30f;
    for (int f = t; f < CDIM; f += 256) {
        float v = xs[f];
        mn = fminf(mn, v); mx = fmaxf(mx, v);
    }
    #pragma unroll
    for (int off = 32; off > 0; off >>= 1) {
        mn = fminf(mn, __shfl_xor(mn, off));
        mx = fmaxf(mx, __shfl_xor(mx, off));
    }
    if (lane == 0) { wred[wv] = mn; wred[4 + wv] = mx; }
    __syncthreads();
    mn = fminf(fminf(wred[0], wred[1]), fminf(wred[2], wred[3]));
    mx = fmaxf(fmaxf(wred[4], wred[5]), fmaxf(wred[6], wred[7]));

    for (int r = 0; r < 16; ++r) {
        const int i = rg * 64 + r * 4 + wv;   // 4 waves -> 4 consecutive rows
        const float xi = xs[i];
        const float li = (xi >= 0.f) ? xi * mn : xi * mx; // min_j(x_i*x_j), exact
        const float nxi = -xi;
        float sum = 0.f, d1 = 0.f, d2 = 0.f;
        #pragma unroll
        for (int g = 0; g < 8; ++g) {
            const int o = g * 256 + lane * 4;
            f32x4 xv = *reinterpret_cast<const f32x4*>(&xs[o]);
            f32x4 v1 = *reinterpret_cast<const f32x4*>(&xs1[o]);
            f32x4 v2 = *reinterpret_cast<const f32x4*>(&xs2[o]);
            #pragma unroll
            for (int c = 0; c < 4; ++c) {
                float ev = __expf(fmaf(nxi, xv[c], li)); // arg <= ~0
                sum += ev;
                d1 = fmaf(ev, v1[c], d1);
                d2 = fmaf(ev, v2[c], d2);
            }
        }
        #pragma unroll
        for (int off = 32; off > 0; off >>= 1) {
            sum += __shfl_xor(sum, off);
            d1  += __shfl_xor(d1, off);
            d2  += __shfl_xor(d2, off);
        }
        const float inv = 1.f / sum;
        if (lane == 0) {
            out1[b * CDIM + i] = fmaf(d1, inv, xs1[i]);
            out2[b * CDIM + i] = fmaf(d2, inv, xs2[i]);
        }
        float* arow = att + (size_t)(b * CDIM + i) * CDIM;
        #pragma unroll
        for (int g = 0; g < 8; ++g) {
            const int o = g * 256 + lane * 4;
            f32x4 xv = *reinterpret_cast<const f32x4*>(&xs[o]);
            f32x4 v;
            #pragma unroll
            for (int c = 0; c < 4; ++c)
                v[c] = __expf(fmaf(nxi, xv[c], li)) * inv;
            *reinterpret_cast<f32x4*>(arow + o) = v;
        }
    }
}

extern "C" void kernel_launch(void* const* d_in, const int* in_sizes, int n_in,
                              void* d_out, int out_size, void* d_ws, size_t ws_size,
                              hipStream_t stream) {
    const float* x1   = (const float*)d_in[0];
    const float* x2   = (const float*)d_in[1];
    const float* W    = (const float*)d_in[2];
    const float* bias = (const float*)d_in[3];
    float* out  = (float*)d_out;
    float* out1 = out;
    float* out2 = out + BATCH * CDIM;
    float* att  = out + 2 * BATCH * CDIM;
    float* xrow = (float*)d_ws;

    // GEMM partials live in the tail of the attention region; fully consumed
    // by reduce_x_k before attn_k overwrites that region.
    float* partial = out + ((size_t)out_size - (size_t)KT * BATCH * CDIM);

    gemm_partial_k<<<dim3(NT, KT), dim3(256), 0, stream>>>(x1, x2, W, partial);
    reduce_x_k<<<(BATCH * CDIM) / 256, 256, 0, stream>>>(partial, bias, xrow);
    attn_k<<<BATCH * (CDIM / 64), 256, 0, stream>>>(xrow, x1, x2, out1, out2, att);
}

// Round 14
// 123.021 us; speedup vs baseline: 1.1575x; 1.1575x over previous
//
#include <hip/hip_runtime.h>

#define CDIM 2048
#define BATCH 32
#define K2 4096
#define BN 64
#define BK 128
#define KT (K2 / BK)    // 32
#define NT (CDIM / BN)  // 32

typedef float f32x4 __attribute__((ext_vector_type(4)));

// ---- GEMM partial (R7): partial[kt] = xcat[:, k0:k0+BK] @ W[:, k0:k0+BK]^T ----
__global__ __launch_bounds__(256) void gemm_partial_k(
    const float* __restrict__ x1, const float* __restrict__ x2,
    const float* __restrict__ W, float* __restrict__ partial)
{
    __shared__ float lds[BN * BK + BATCH * BK];
    float* Wt = lds;
    float* Xs = lds + BN * BK;

    const int nt = blockIdx.x, kt = blockIdx.y;
    const int i0 = nt * BN, k0 = kt * BK;
    const int t = threadIdx.x;
    const int lane = t & 63, ks = t >> 6;
    const int cg8 = lane & 7, bg = lane >> 3;

    const float* xsrc = (k0 < CDIM) ? x1 : x2;
    const int kk0 = k0 & (CDIM - 1);

    #pragma unroll
    for (int r = 0; r < 8; ++r) {
        int f = t + 256 * r;
        int row = f >> 5, kc = f & 31;
        float4 v = *reinterpret_cast<const float4*>(W + (size_t)(i0 + row) * K2 + k0 + kc * 4);
        int sc = kc ^ ((row >> 3) & 7);
        *reinterpret_cast<float4*>(&Wt[row * BK + sc * 4]) = v;
    }
    #pragma unroll
    for (int r = 0; r < 4; ++r) {
        int f = t + 256 * r;
        int row = f >> 5, kc = f & 31;
        float4 v = *reinterpret_cast<const float4*>(xsrc + row * CDIM + kk0 + kc * 4);
        int sc = kc ^ ((row >> 2) & 7);
        *reinterpret_cast<float4*>(&Xs[row * BK + sc * 4]) = v;
    }
    __syncthreads();

    float acc[4][8] = {};
    #pragma unroll 2
    for (int s = 0; s < 8; ++s) {
        const int kc = ks * 8 + s;
        f32x4 xv[4], wv[8];
        #pragma unroll
        for (int bb = 0; bb < 4; ++bb)
            xv[bb] = *reinterpret_cast<const f32x4*>(&Xs[(4 * bg + bb) * BK + (kc ^ bg) * 4]);
        #pragma unroll
        for (int cc = 0; cc < 8; ++cc)
            wv[cc] = *reinterpret_cast<const f32x4*>(&Wt[(8 * cg8 + cc) * BK + (kc ^ cg8) * 4]);
        #pragma unroll
        for (int bb = 0; bb < 4; ++bb)
            #pragma unroll
            for (int cc = 0; cc < 8; ++cc)
                #pragma unroll
                for (int w = 0; w < 4; ++w)
                    acc[bb][cc] = fmaf(xv[bb][w], wv[cc][w], acc[bb][cc]);
    }

    __syncthreads();
    float* accS = lds;
    #pragma unroll
    for (int bb = 0; bb < 4; ++bb)
        #pragma unroll
        for (int cc = 0; cc < 8; ++cc)
            accS[(ks * 64 + lane) * 33 + bb * 8 + cc] = acc[bb][cc];
    __syncthreads();

    {
        const int l0 = t >> 2, q = t & 3;
        float s0[8];
        #pragma unroll
        for (int j = 0; j < 8; ++j) {
            float s = 0.f;
            #pragma unroll
            for (int k = 0; k < 4; ++k)
                s += accS[(k * 64 + l0) * 33 + q * 8 + j];
            s0[j] = s;
        }
        const int b_row = 4 * (l0 >> 3) + q;
        const int icol  = 8 * (l0 & 7);
        float* dst = partial + (size_t)kt * (BATCH * CDIM) + b_row * CDIM + i0 + icol;
        *reinterpret_cast<float4*>(dst)     = make_float4(s0[0], s0[1], s0[2], s0[3]);
        *reinterpret_cast<float4*>(dst + 4) = make_float4(s0[4], s0[5], s0[6], s0[7]);
    }
}

__global__ __launch_bounds__(256) void reduce_x_k(
    const float* __restrict__ partial, const float* __restrict__ bias,
    float* __restrict__ x)
{
    int idx = blockIdx.x * 256 + threadIdx.x;
    float s = 0.f;
    #pragma unroll
    for (int kt = 0; kt < KT; ++kt) s += partial[(size_t)kt * (BATCH * CDIM) + idx];
    x[idx] = s + bias[idx & (CDIM - 1)];
}

// ---- Attention (R7, best measured): att[b,i,j] = softmax_j(-x_i x_j);
// out = att@x{1,2} + x{1,2}. Two-pass (sums, then recompute-exp + store);
// steady-state at the measured HBM-write ceiling (R6: 6.5 TB/s, FETCH 3 MB,
// zero bank conflicts). ----
__global__ __launch_bounds__(256) void attn_k(
    const float* __restrict__ x, const float* __restrict__ x1,
    const float* __restrict__ x2, float* __restrict__ out1,
    float* __restrict__ out2, float* __restrict__ att)
{
    __shared__ float xs[CDIM];
    __shared__ float xs1[CDIM];
    __shared__ float xs2[CDIM];
    __shared__ float wred[8];
    const int b = blockIdx.x >> 5, rg = blockIdx.x & 31;
    const int t = threadIdx.x;
    const int lane = t & 63, wv = t >> 6;
    const float* xb  = x  + b * CDIM;
    const float* x1b = x1 + b * CDIM;
    const float* x2b = x2 + b * CDIM;

    #pragma unroll
    for (int r = 0; r < 2; ++r) {
        int f = (t + 256 * r) * 4;
        *reinterpret_cast<float4*>(&xs[f])  = *reinterpret_cast<const float4*>(xb  + f);
        *reinterpret_cast<float4*>(&xs1[f]) = *reinterpret_cast<const float4*>(x1b + f);
        *reinterpret_cast<float4*>(&xs2[f]) = *reinterpret_cast<const float4*>(x2b + f);
    }
    __syncthreads();

    // block min/max of x[b,:]
    float mn = 1e30f, mx = -1e30f;
    for (int f = t; f < CDIM; f += 256) {
        float v = xs[f];
        mn = fminf(mn, v); mx = fmaxf(mx, v);
    }
    #pragma unroll
    for (int off = 32; off > 0; off >>= 1) {
        mn = fminf(mn, __shfl_xor(mn, off));
        mx = fmaxf(mx, __shfl_xor(mx, off));
    }
    if (lane == 0) { wred[wv] = mn; wred[4 + wv] = mx; }
    __syncthreads();
    mn = fminf(fminf(wred[0], wred[1]), fminf(wred[2], wred[3]));
    mx = fmaxf(fmaxf(wred[4], wred[5]), fmaxf(wred[6], wred[7]));

    for (int r = 0; r < 16; ++r) {
        const int i = rg * 64 + wv * 16 + r;
        const float xi = xs[i];
        const float li = (xi >= 0.f) ? xi * mn : xi * mx; // min_j(x_i*x_j), exact
        const float nxi = -xi;
        float sum = 0.f, d1 = 0.f, d2 = 0.f;
        // pass 1: denominator + the two matvec dots
        #pragma unroll
        for (int g = 0; g < 8; ++g) {
            const int o = g * 256 + lane * 4;
            f32x4 xv = *reinterpret_cast<const f32x4*>(&xs[o]);
            f32x4 v1 = *reinterpret_cast<const f32x4*>(&xs1[o]);
            f32x4 v2 = *reinterpret_cast<const f32x4*>(&xs2[o]);
            #pragma unroll
            for (int c = 0; c < 4; ++c) {
                float ev = __expf(fmaf(nxi, xv[c], li)); // arg <= ~0
                sum += ev;
                d1 = fmaf(ev, v1[c], d1);
                d2 = fmaf(ev, v2[c], d2);
            }
        }
        #pragma unroll
        for (int off = 32; off > 0; off >>= 1) {
            sum += __shfl_xor(sum, off);
            d1  += __shfl_xor(d1, off);
            d2  += __shfl_xor(d2, off);
        }
        const float inv = 1.f / sum;
        if (lane == 0) {
            out1[b * CDIM + i] = fmaf(d1, inv, xs1[i]);
            out2[b * CDIM + i] = fmaf(d2, inv, xs2[i]);
        }
        // pass 2: recompute exp, scale, store
        float* arow = att + (size_t)(b * CDIM + i) * CDIM;
        #pragma unroll
        for (int g = 0; g < 8; ++g) {
            const int o = g * 256 + lane * 4;
            f32x4 xv = *reinterpret_cast<const f32x4*>(&xs[o]);
            f32x4 v;
            #pragma unroll
            for (int c = 0; c < 4; ++c)
                v[c] = __expf(fmaf(nxi, xv[c], li)) * inv;
            *reinterpret_cast<f32x4*>(arow + o) = v;
        }
    }
}

extern "C" void kernel_launch(void* const* d_in, const int* in_sizes, int n_in,
                              void* d_out, int out_size, void* d_ws, size_t ws_size,
                              hipStream_t stream) {
    const float* x1   = (const float*)d_in[0];
    const float* x2   = (const float*)d_in[1];
    const float* W    = (const float*)d_in[2];
    const float* bias = (const float*)d_in[3];
    float* out  = (float*)d_out;
    float* out1 = out;
    float* out2 = out + BATCH * CDIM;
    float* att  = out + 2 * BATCH * CDIM;
    float* xrow = (float*)d_ws;

    // GEMM partials live in the tail of the attention region; fully consumed
    // by reduce_x_k before attn_k overwrites that region.
    float* partial = out + ((size_t)out_size - (size_t)KT * BATCH * CDIM);

    gemm_partial_k<<<dim3(NT, KT), dim3(256), 0, stream>>>(x1, x2, W, partial);
    reduce_x_k<<<(BATCH * CDIM) / 256, 256, 0, stream>>>(partial, bias, xrow);
    attn_k<<<BATCH * (CDIM / 64), 256, 0, stream>>>(xrow, x1, x2, out1, out2, att);
}